// Round 1
// baseline (343.404 us; speedup 1.0000x reference)
//
#include <hip/hip_runtime.h>
#include <math.h>

// Problem shapes
constexpr int B = 4, H = 16, S = 1024, D = 256, P = 64;
constexpr long long N_ROWS = (long long)B * H * S;            // 65536
// Output segment offsets (floats, concatenated in return order)
constexpr long long OFF_RT = 0;                               // routing_scores
constexpr long long SZ_RT  = N_ROWS;                          // 65536
constexpr long long OFF_OR = OFF_RT + SZ_RT;                  // optimal_routes
constexpr long long SZ_OR  = N_ROWS * (long long)S;           // 67108864
constexpr long long OFF_TW = OFF_OR + SZ_OR;                  // transfer_weights
constexpr long long SZ_TW  = 16LL * 64 * 64;                  // 65536
constexpr long long OFF_PS = OFF_TW + SZ_TW;                  // pattern_scores

typedef _Float16 half8   __attribute__((ext_vector_type(8)));
typedef _Float16 half4v  __attribute__((ext_vector_type(4)));
typedef float    floatx4 __attribute__((ext_vector_type(4)));

// LDS row stride for B tiles: 256 + 8 halves (16-B pad) keeps ds_read_b128
// 16-B aligned and balances the 16-lane fragment reads across banks.
constexpr int BSTRIDE = 264;

// Fused-grid layout:
//   [0, 512)            gemm blocks (128 states-rows each, start first)
//   [512, 640)          small segments (routing_scores fill + tw copy)
//   [640, 640+4096)     optimal_routes fill, 16 float4/thread (64 KB/block)
// R9: single launch. The gemm no longer depends on a prep kernel — each gemm
// block recomputes the normalized-pattern h/l split into LDS itself (64 KB
// L2-resident read + ~0.8 us of shuffles). Route fill fattened 16x: the old
// 65536 one-store blocks were dispatch-grain-bound; value is tid-periodic so
// it is computed once and stored 16x.
constexpr int GEMM_BLOCKS  = 512;
constexpr int SMALL_BLOCKS = 128;
constexpr int ROUTE_F4_PER_THREAD = 16;
constexpr int ROUTE_BLOCKS =
    (int)((SZ_OR / 4) / (256LL * ROUTE_F4_PER_THREAD));       // 4096

__global__ __launch_bounds__(256) void k_fused(
        const float* __restrict__ states,
        const float* __restrict__ pat,
        const floatx4* __restrict__ tw,
        float* __restrict__ out) {
    __shared__ _Float16 smem[2 * P * BSTRIDE];                // 66 KB
    int blk = blockIdx.x;
    int tid = threadIdx.x;

    if (blk >= GEMM_BLOCKS) {
        if (blk < GEMM_BLOCKS + SMALL_BLOCKS) {
            // routing_scores = 1/1024 everywhere; tw passthrough copy
            int i = (blk - GEMM_BLOCKS) * 256 + tid;          // 0..32767
            constexpr int Q = (int)(SZ_RT / 4);               // 16384 float4
            if (i < Q) {
                floatx4 v = { 0.0009765625f, 0.0009765625f,
                              0.0009765625f, 0.0009765625f };
                ((floatx4*)(out + OFF_RT))[i] = v;
            } else {
                ((floatx4*)(out + OFF_TW))[i - Q] = tw[i - Q];
            }
        } else {
            // optimal_routes: d_final[j] = -j/1024, 1024-periodic, broadcast
            // over all rows. (i*4)&1023 == tid*4 for every chunk this thread
            // writes, so the float4 value is computed once.
            long long rb = blk - GEMM_BLOCKS - SMALL_BLOCKS;  // 0..4095
            float b0 = (float)(tid << 2) * (-0.0009765625f);
            floatx4 v;
            v.x = b0;
            v.y = b0 - 0.0009765625f;
            v.z = b0 - 0.001953125f;
            v.w = b0 - 0.0029296875f;
            floatx4* dst = (floatx4*)(out + OFF_OR)
                         + rb * (256LL * ROUTE_F4_PER_THREAD) + tid;
            #pragma unroll
            for (int k = 0; k < ROUTE_F4_PER_THREAD; ++k)
                dst[k * 256] = v;                             // 4 KB/wave-store
        }
        return;
    }

    // ---------------- GEMM + row softmax (blk 0..511) ----------------------
    _Float16* smH = smem;
    _Float16* smL = smem + P * BSTRIDE;

    int tid_ = tid;
    int wave = tid_ >> 6;
    int lane = tid_ & 63;

    // Phase 0: load patterns (fp32, L2-resident), normalize with folded
    // 1/T = 10, split into f16 hi/lo directly into LDS. One pattern per wave
    // per iteration; math identical to the old prep kernel (bitwise-same).
    #pragma unroll 4
    for (int i = 0; i < 16; ++i) {
        int p = wave * 16 + i;
        floatx4 v = ((const floatx4*)(pat + (long long)p * D))[lane];
        float ss = v.x * v.x + v.y * v.y + v.z * v.z + v.w * v.w;
        #pragma unroll
        for (int m = 1; m < 64; m <<= 1) ss += __shfl_xor(ss, m, 64);
        float scale = 10.0f / fmaxf(sqrtf(ss), 1e-12f);
        half4v hh, ll;
        #pragma unroll
        for (int j = 0; j < 4; ++j) {
            float a = v[j] * scale;
            _Float16 h = (_Float16)a;
            hh[j] = h;
            ll[j] = (_Float16)(a - (float)h);
        }
        *(half4v*)&smH[p * BSTRIDE + lane * 4] = hh;
        *(half4v*)&smL[p * BSTRIDE + lane * 4] = ll;
    }
    __syncthreads();

    // Phase 1: sims = states @ pn^T via f16 split-precision MFMA.
    // Wave tile 32 rows x 64 patterns (R8): each LDS B-fragment pair feeds
    // 6 MFMAs. acc = 2 row sets x 4 N-tiles x 4 = 32 VGPRs.
    int q = lane >> 4;                     // quad 0..3
    int m = lane & 15;
    long long row0 = (long long)blk * 128 + wave * 32;
    const float* __restrict__ arow0 = states + (row0 + m) * D + q * 8;
    const float* __restrict__ arow1 = arow0 + 16 * D;

    floatx4 acc0[4] = {floatx4{0,0,0,0}, floatx4{0,0,0,0},
                       floatx4{0,0,0,0}, floatx4{0,0,0,0}};
    floatx4 acc1[4] = {floatx4{0,0,0,0}, floatx4{0,0,0,0},
                       floatx4{0,0,0,0}, floatx4{0,0,0,0}};

    float4 n0 = *(const float4*)(arow0);
    float4 n1 = *(const float4*)(arow0 + 4);
    float4 n2 = *(const float4*)(arow1);
    float4 n3 = *(const float4*)(arow1 + 4);
    #pragma unroll
    for (int kk = 0; kk < 8; ++kk) {
        float av0[8] = { n0.x, n0.y, n0.z, n0.w, n1.x, n1.y, n1.z, n1.w };
        float av1[8] = { n2.x, n2.y, n2.z, n2.w, n3.x, n3.y, n3.z, n3.w };
        if (kk < 7) {                                 // prefetch next A chunks
            n0 = *(const float4*)(arow0 + (kk + 1) * 32);
            n1 = *(const float4*)(arow0 + (kk + 1) * 32 + 4);
            n2 = *(const float4*)(arow1 + (kk + 1) * 32);
            n3 = *(const float4*)(arow1 + (kk + 1) * 32 + 4);
        }
        half8 ah0, al0, ah1, al1;
        #pragma unroll
        for (int j = 0; j < 8; ++j) {
            _Float16 h0 = (_Float16)av0[j];
            ah0[j] = h0;
            al0[j] = (_Float16)(av0[j] - (float)h0);
            _Float16 h1 = (_Float16)av1[j];
            ah1[j] = h1;
            al1[j] = (_Float16)(av1[j] - (float)h1);
        }
        #pragma unroll
        for (int t = 0; t < 4; ++t) {
            int boff = (t * 16 + m) * BSTRIDE + kk * 32 + q * 8;
            half8 bh = *(const half8*)&smH[boff];
            half8 bl = *(const half8*)&smL[boff];
            acc0[t] = __builtin_amdgcn_mfma_f32_16x16x32_f16(ah0, bh, acc0[t], 0, 0, 0);
            acc0[t] = __builtin_amdgcn_mfma_f32_16x16x32_f16(al0, bh, acc0[t], 0, 0, 0);
            acc0[t] = __builtin_amdgcn_mfma_f32_16x16x32_f16(ah0, bl, acc0[t], 0, 0, 0);
            acc1[t] = __builtin_amdgcn_mfma_f32_16x16x32_f16(ah1, bh, acc1[t], 0, 0, 0);
            acc1[t] = __builtin_amdgcn_mfma_f32_16x16x32_f16(al1, bh, acc1[t], 0, 0, 0);
            acc1[t] = __builtin_amdgcn_mfma_f32_16x16x32_f16(ah1, bl, acc1[t], 0, 0, 0);
        }
    }

    // Row softmax per row set: row = q*4 + r lives in the 16 lanes sharing q
    // (shuffle masks 1..8 stay in-group); lane holds 4 cols (one per N-tile).
    float* out_ps = out + OFF_PS;
    #pragma unroll
    for (int set = 0; set < 2; ++set) {
        floatx4* acc = set ? acc1 : acc0;
        long long rbase = row0 + set * 16;
        #pragma unroll
        for (int r = 0; r < 4; ++r) {
            float mx = fmaxf(fmaxf(acc[0][r], acc[1][r]),
                             fmaxf(acc[2][r], acc[3][r]));
            #pragma unroll
            for (int msk = 1; msk < 16; msk <<= 1)
                mx = fmaxf(mx, __shfl_xor(mx, msk, 64));
            float e[4];
            float s = 0.0f;
            #pragma unroll
            for (int t = 0; t < 4; ++t) { e[t] = __expf(acc[t][r] - mx); s += e[t]; }
            #pragma unroll
            for (int msk = 1; msk < 16; msk <<= 1) s += __shfl_xor(s, msk, 64);
            float inv = 1.0f / s;
            long long row = rbase + q * 4 + r;
            #pragma unroll
            for (int t = 0; t < 4; ++t) {
                out_ps[row * P + t * 16 + m] = e[t] * inv;
            }
        }
    }
}

// ---------------------------------------------------------------------------
extern "C" void kernel_launch(void* const* d_in, const int* in_sizes, int n_in,
                              void* d_out, int out_size, void* d_ws, size_t ws_size,
                              hipStream_t stream) {
    const float* states   = (const float*)d_in[0];   // (4,16,1024,256) fp32
    const float* patterns = (const float*)d_in[1];   // (64,256) fp32
    const float* transfer = (const float*)d_in[2];   // (16,64,64) fp32
    float* out = (float*)d_out;

    k_fused<<<dim3(GEMM_BLOCKS + SMALL_BLOCKS + ROUTE_BLOCKS), dim3(256), 0,
              stream>>>(states, patterns, (const floatx4*)transfer, out);
}